// Round 4
// baseline (1251.182 us; speedup 1.0000x reference)
//
#include <hip/hip_runtime.h>
#include <math.h>

// FCCaps dynamic routing, MI355X.
// Shapes: B=128, I=2048, J=6 (OUT_CAPS of 8), O=16, Cin=32, MAX_ITERS=16.
// Pipeline: init -> p0 (u_hat einsum, 1 i/block, float4 stores)
//           -> r0 (Sum_i u_hat partials from L3, 32 psets)
//           -> 16x g (fused routing iteration, device-side early-exit)
//           -> final (poses + activations).

#define B_    128
#define I_    2048
#define J_    6
#define O_    16
#define JO_   96
#define CIN_  32
#define MAXIT 16
#define NCH   8            // i-chunks for g kernel (256 i each)
#define NPS   32           // i-subchunks for r0 (64 i each)

// ---------------- init: zero b logits, zero kde slots ------------------------
__global__ __launch_bounds__(256) void init_kernel(float* __restrict__ b_buf,
                                                   float* __restrict__ kde_acc) {
  int idx = blockIdx.x * 256 + threadIdx.x;
  b_buf[idx] = 0.0f;                               // grid sized exactly B*I*J
  if (idx < MAXIT) kde_acc[idx] = 0.0f;
}

// ---------------- p0: u_hat[b][i][jo] = sum_c W1[i][jo][c] * x[b][i][c] ------
// One i per block. 256 thr: oq = t&3 (owns o = oq*4..+3), bg = t>>2 (2 b each).
// LDS: W[96][36] + x[128][36] (pad 36 kills power-of-2 bank strides).
__global__ __launch_bounds__(256, 4) void p0_kernel(const float* __restrict__ x,
                                                    const float* __restrict__ W1,
                                                    float* __restrict__ u_hat) {
  __shared__ float Ws[96 * 36];
  __shared__ float xs[128 * 36];
  const int t = threadIdx.x;
  const int i = blockIdx.x;

  // stage W: 768 float4 (only first 3072 floats of the 4096-float row, j<6)
  const float* wsrc = W1 + (size_t)i * 4096;
#pragma unroll
  for (int q = 0; q < 3; q++) {
    int f = t + 256 * q;                        // float4 index 0..767
    float4 w = *(const float4*)(wsrc + f * 4);
    int row = f >> 3, col = (f & 7) * 4;
    *(float4*)(&Ws[row * 36 + col]) = w;
  }
  // stage x: 1024 float4 (128 b x 32 c)
#pragma unroll
  for (int q = 0; q < 4; q++) {
    int p = t + 256 * q;                        // float4 index 0..1023
    int bl = p >> 3, c4 = p & 7;
    float4 v = *(const float4*)(x + ((size_t)bl * I_ + i) * CIN_ + c4 * 4);
    *(float4*)(&xs[bl * 36 + c4 * 4]) = v;
  }
  __syncthreads();

  const int oq = t & 3, bg = t >> 2;
  float4 acc[2][6];
#pragma unroll
  for (int bb = 0; bb < 2; bb++)
#pragma unroll
    for (int j = 0; j < 6; j++) acc[bb][j] = make_float4(0.f, 0.f, 0.f, 0.f);

#pragma unroll
  for (int cq = 0; cq < 8; cq++) {
    float4 xv[2];
    xv[0] = *(const float4*)(&xs[(bg * 2 + 0) * 36 + cq * 4]);
    xv[1] = *(const float4*)(&xs[(bg * 2 + 1) * 36 + cq * 4]);
#pragma unroll
    for (int j = 0; j < 6; j++) {
      const float* wb = &Ws[(j * 16 + oq * 4) * 36 + cq * 4];
      float4 w0 = *(const float4*)(wb);
      float4 w1 = *(const float4*)(wb + 36);
      float4 w2 = *(const float4*)(wb + 72);
      float4 w3 = *(const float4*)(wb + 108);
#pragma unroll
      for (int bb = 0; bb < 2; bb++) {
        acc[bb][j].x += w0.x * xv[bb].x + w0.y * xv[bb].y + w0.z * xv[bb].z + w0.w * xv[bb].w;
        acc[bb][j].y += w1.x * xv[bb].x + w1.y * xv[bb].y + w1.z * xv[bb].z + w1.w * xv[bb].w;
        acc[bb][j].z += w2.x * xv[bb].x + w2.y * xv[bb].y + w2.z * xv[bb].z + w2.w * xv[bb].w;
        acc[bb][j].w += w3.x * xv[bb].x + w3.y * xv[bb].y + w3.z * xv[bb].z + w3.w * xv[bb].w;
      }
    }
  }

#pragma unroll
  for (int bb = 0; bb < 2; bb++) {
    size_t base = ((size_t)(bg * 2 + bb) * I_ + i) * JO_;
#pragma unroll
    for (int j = 0; j < 6; j++)
      *(float4*)(&u_hat[base + j * 16 + oq * 4]) = acc[bb][j];
  }
}

// ---------------- r0: r0buf[ps][b][jo] = (1/6) * sum of 64 i of u_hat --------
__global__ __launch_bounds__(256) void r0_kernel(const float* __restrict__ u_hat,
                                                 float* __restrict__ r0buf) {
  int idx = blockIdx.x * 256 + threadIdx.x;      // 0..98303 (quad outputs)
  int joq = idx % 24;
  int rb = idx / 24;
  int b = rb % B_;
  int ps = rb / B_;                              // 0..31
  const float* src = u_hat + ((size_t)b * I_ + ps * 64) * JO_ + joq * 4;
  float4 s = make_float4(0.f, 0.f, 0.f, 0.f);
#pragma unroll 8
  for (int k = 0; k < 64; k++) {
    float4 v = *(const float4*)(src + (size_t)k * JO_);
    s.x += v.x; s.y += v.y; s.z += v.z; s.w += v.w;
  }
  const float c = 1.0f / 6.0f;
  *(float4*)(&r0buf[((size_t)ps * B_ + b) * JO_ + joq * 4]) =
      make_float4(s.x * c, s.y * c, s.z * c, s.w * c);
}

// ---------------- softmax over 6 (thread-local) ------------------------------
__device__ __forceinline__ void softmax6(const float* bv, float* s) {
  float m = fmaxf(fmaxf(fmaxf(bv[0], bv[1]), fmaxf(bv[2], bv[3])), fmaxf(bv[4], bv[5]));
  float e[6], sum = 0.0f;
#pragma unroll
  for (int j = 0; j < 6; j++) { e[j] = expf(bv[j] - m); sum += e[j]; }
  float inv = 1.0f / sum;
#pragma unroll
  for (int j = 0; j < 6; j++) s[j] = e[j] * inv;
}

// ---------------- g: one fused routing iteration -----------------------------
// grid (NCH=8, B=128), 256 thr. Computes v_t from prev partials (redundant per
// block), then dd / b-update / kde partial / next-iteration partials.
__global__ __launch_bounds__(256) void g_kernel(int t, int npart,
    const float* __restrict__ u_hat, float* __restrict__ b_buf,
    const float* __restrict__ gp_in, float* __restrict__ gp_out,
    const float* __restrict__ sp_in, float* __restrict__ sp_out,
    float* __restrict__ v_buf, float* __restrict__ kde_acc) {
  // reconstruct done/loss chain from kde slots (all threads, uniform)
  float last = 0.0f; bool done = false;
  for (int tau = 1; tau < t; ++tau) {
    float kde = logf(kde_acc[tau - 1] * (1.0f / 128.0f));
    bool conv = fabsf(kde - last) < 0.05f;
    if (!done) last = kde;
    done = done || conv;
  }
  if (done) return;                               // frozen: outputs already final

  const int t0 = threadIdx.x;
  const int b = blockIdx.y;
  const int chunk = blockIdx.x;

  __shared__ float vS[96], v2S[6], SS[6], iSS[6], gSc[6], slots[8][56];

  if (t0 < 6) { float s;
    if (t == 1) s = 2048.0f / 6.0f;
    else { s = 0.0f; for (int c = 0; c < NCH; c++) s += sp_in[(c * B_ + b) * J_ + t0]; }
    SS[t0] = s; iSS[t0] = 1.0f / s; }
  __syncthreads();
  if (t0 < 96) { float u = 0;
    for (int c = 0; c < npart; c++) u += gp_in[((size_t)c * B_ + b) * JO_ + t0];
    vS[t0] = u / SS[t0 >> 4]; }                   // pre-squash v
  __syncthreads();
  if (t0 < 6) { float s2 = 0;
    for (int o = 0; o < 16; o++) { float v = vS[t0 * 16 + o]; s2 += v * v; }
    float g = sqrtf(s2) / (0.5f + s2); gSc[t0] = g; v2S[t0] = g * g * s2; }
  __syncthreads();
  if (t0 < 96) { float v = vS[t0] * gSc[t0 >> 4]; vS[t0] = v;
    if (chunk == 0) v_buf[b * JO_ + t0] = v; }    // commit v_t (only if active)
  __syncthreads();

  const int h = t0 & 1;                           // o-half
  float Upart[6][8] = {}; float sPart[6] = {}; float cdd = 0.0f;

#pragma unroll 1
  for (int half = 0; half < 2; ++half) {
    int i = chunk * 256 + half * 128 + (t0 >> 1);
    size_t bbase = ((size_t)b * I_ + i) * J_;
    float bo[6], sm[6];
#pragma unroll
    for (int j = 0; j < 6; j++) bo[j] = b_buf[bbase + j];
    softmax6(bo, sm);                             // s_t (c_t = s_t / S_t)

    const float* urow = u_hat + ((size_t)b * I_ + i) * JO_ + h * 8;
    float dd[6];
#pragma unroll
    for (int j = 0; j < 6; j++) {
      float4 ua = *(const float4*)(urow + j * 16);
      float4 ub = *(const float4*)(urow + j * 16 + 4);
      float4 va = *(const float4*)(&vS[j * 16 + h * 8]);
      float4 vb = *(const float4*)(&vS[j * 16 + h * 8 + 4]);
      float p2 = ua.x*ua.x + ua.y*ua.y + ua.z*ua.z + ua.w*ua.w
               + ub.x*ub.x + ub.y*ub.y + ub.z*ub.z + ub.w*ub.w;
      float pd = ua.x*va.x + ua.y*va.y + ua.z*va.z + ua.w*va.w
               + ub.x*vb.x + ub.y*vb.y + ub.z*vb.z + ub.w*vb.w;
      p2 += __shfl_xor(p2, 1);                    // full |u|^2 over 16 o
      pd += __shfl_xor(pd, 1);                    // full u.v
      float g = sqrtf(p2) / (0.5f + p2);          // squash scale of u_hat
      dd[j] = 1.0f - (g * g * p2 - 2.0f * g * pd + v2S[j]);
    }
    float bn[6], sn[6];
#pragma unroll
    for (int j = 0; j < 6; j++) bn[j] = bo[j] + dd[j];
    if (h == 0) {
#pragma unroll
      for (int j = 0; j < 6; j++) b_buf[bbase + j] = bn[j];
      float cs = 0.0f;
#pragma unroll
      for (int j = 0; j < 6; j++) cs += (sm[j] * iSS[j]) * dd[j];
      cdd += cs;
    }
    softmax6(bn, sn);                             // s_{t+1}
    if (h == 0) {
#pragma unroll
      for (int j = 0; j < 6; j++) sPart[j] += sn[j];
    }
#pragma unroll
    for (int j = 0; j < 6; j++) {                 // reload u (L1/L2-hot) to cut regs
      float4 ua = *(const float4*)(urow + j * 16);
      float4 ub = *(const float4*)(urow + j * 16 + 4);
      Upart[j][0] += sn[j] * ua.x; Upart[j][1] += sn[j] * ua.y;
      Upart[j][2] += sn[j] * ua.z; Upart[j][3] += sn[j] * ua.w;
      Upart[j][4] += sn[j] * ub.x; Upart[j][5] += sn[j] * ub.y;
      Upart[j][6] += sn[j] * ub.z; Upart[j][7] += sn[j] * ub.w;
    }
  }

  // same-parity butterfly (bits 1..5): sums the 32 lanes sharing this h
#pragma unroll
  for (int m = 2; m <= 32; m <<= 1) {
#pragma unroll
    for (int j = 0; j < 6; j++) {
#pragma unroll
      for (int r = 0; r < 8; r++) Upart[j][r] += __shfl_xor(Upart[j][r], m);
      sPart[j] += __shfl_xor(sPart[j], m);
    }
    cdd += __shfl_xor(cdd, m);
  }
  int lane = t0 & 63, w = t0 >> 6;
  if (lane < 2) {
#pragma unroll
    for (int j = 0; j < 6; j++) {
#pragma unroll
      for (int r = 0; r < 8; r++) slots[w * 2 + lane][j * 8 + r] = Upart[j][r];
      slots[w * 2 + lane][48 + j] = sPart[j];
    }
    slots[w * 2 + lane][54] = cdd;
  }
  __syncthreads();
  if (t0 < 96) {
    int j = t0 >> 4, o = t0 & 15, hh = o >> 3, r = o & 7;
    float s = slots[0 + hh][j * 8 + r] + slots[2 + hh][j * 8 + r] +
              slots[4 + hh][j * 8 + r] + slots[6 + hh][j * 8 + r];
    gp_out[((size_t)chunk * B_ + b) * JO_ + t0] = s;
  } else if (t0 < 102) {
    int j = t0 - 96;
    float s = slots[0][48 + j] + slots[2][48 + j] + slots[4][48 + j] + slots[6][48 + j];
    sp_out[(chunk * B_ + b) * J_ + j] = s;
  } else if (t0 == 102) {
    float s = slots[0][54] + slots[2][54] + slots[4][54] + slots[6][54];
    atomicAdd(&kde_acc[t - 1], s);
  }
}

// ---------------- final: poses = v, activations = |v| ------------------------
__global__ __launch_bounds__(256) void final_kernel(const float* __restrict__ v_buf,
                                                    float* __restrict__ out) {
  int idx = blockIdx.x * 256 + threadIdx.x;       // 0..12287 = b*96 + j*16 + o
  float v = v_buf[idx];
  out[idx] = v;
  float p = v * v;
  p += __shfl_xor(p, 1); p += __shfl_xor(p, 2);
  p += __shfl_xor(p, 4); p += __shfl_xor(p, 8);
  if ((idx & 15) == 0) out[B_ * JO_ + (idx >> 4)] = sqrtf(p);
}

// ---------------- launch -----------------------------------------------------
extern "C" void kernel_launch(void* const* d_in, const int* in_sizes, int n_in,
                              void* d_out, int out_size, void* d_ws, size_t ws_size,
                              hipStream_t stream) {
  const float* x  = (const float*)d_in[0];
  const float* W1 = (const float*)d_in[2];        // d_in[1] = y, unused by reference

  float* ws    = (float*)d_ws;
  float* u_hat = ws;                                        // 25,165,824
  float* b_buf = u_hat + (size_t)B_ * I_ * JO_;             //  1,572,864
  float* r0buf = b_buf + (size_t)B_ * I_ * J_;              //    393,216
  float* gp    = r0buf + (size_t)NPS * B_ * JO_;            //  2 * 98,304
  float* sp    = gp + 2 * (size_t)NCH * B_ * JO_;           //  2 * 6,144
  float* v_buf = sp + 2 * (size_t)NCH * B_ * J_;            //     12,288
  float* kde   = v_buf + (size_t)B_ * JO_;                  //     16

  init_kernel<<<(B_ * I_ * J_) / 256, 256, 0, stream>>>(b_buf, kde);
  p0_kernel<<<I_, 256, 0, stream>>>(x, W1, u_hat);
  r0_kernel<<<(NPS * B_ * JO_ / 4) / 256, 256, 0, stream>>>(u_hat, r0buf);
  for (int t = 1; t <= MAXIT; t++)
    g_kernel<<<dim3(NCH, B_), 256, 0, stream>>>(t, (t == 1) ? NPS : NCH, u_hat, b_buf,
        (t == 1) ? r0buf : gp + ((t - 1) & 1) * (NCH * B_ * JO_),
        gp + (t & 1) * (NCH * B_ * JO_),
        sp + ((t - 1) & 1) * (NCH * B_ * J_),  sp + (t & 1) * (NCH * B_ * J_),
        v_buf, kde);
  final_kernel<<<(B_ * JO_) / 256, 256, 0, stream>>>(v_buf, (float*)d_out);
}

// Round 6
// 680.070 us; speedup vs baseline: 1.8398x; 1.8398x over previous
//
#include <hip/hip_runtime.h>
#include <math.h>

// FCCaps dynamic routing, MI355X.
// Shapes: B=128, I=2048, J=6 (OUT_CAPS of 8), O=16, Cin=32, MAX_ITERS=16.
// Pipeline: init -> p0 (u_hat einsum, 1 i/block, float4 stores)
//           -> r0 (Sum_i u_hat partials from L3, 32 psets)
//           -> 16x g (fused routing iteration, device-side early-exit)
//           -> final (poses + activations).

#define B_    128
#define I_    2048
#define J_    6
#define O_    16
#define JO_   96
#define CIN_  32
#define MAXIT 16
#define NCH   8            // i-chunks for g kernel (256 i each)
#define NPS   32           // i-subchunks for r0 (64 i each)

// ---------------- init: zero b logits, zero kde slots ------------------------
__global__ __launch_bounds__(256) void init_kernel(float* __restrict__ b_buf,
                                                   float* __restrict__ kde_acc) {
  int idx = blockIdx.x * 256 + threadIdx.x;
  b_buf[idx] = 0.0f;                               // grid sized exactly B*I*J
  if (idx < MAXIT) kde_acc[idx] = 0.0f;
}

// ---------------- p0: u_hat[b][i][jo] = sum_c W1[i][jo][c] * x[b][i][c] ------
// One i per block. 256 thr: oq = t&3 (owns o = oq*4..+3), bg = t>>2 (2 b each).
// LDS: W[96][36] + x[128][36] (pad 36 kills power-of-2 bank strides).
// NOTE: __launch_bounds__(256,4) here caps VGPR at 64 -> accumulator spills
// to scratch -> 3.4 GB HBM traffic, 1 ms (round-4 counters). Keep plain (256).
__global__ __launch_bounds__(256) void p0_kernel(const float* __restrict__ x,
                                                 const float* __restrict__ W1,
                                                 float* __restrict__ u_hat) {
  __shared__ float Ws[96 * 36];
  __shared__ float xs[128 * 36];
  const int t = threadIdx.x;
  const int i = blockIdx.x;

  // stage W: 768 float4 (only first 3072 floats of the 4096-float row, j<6)
  const float* wsrc = W1 + (size_t)i * 4096;
#pragma unroll
  for (int q = 0; q < 3; q++) {
    int f = t + 256 * q;                        // float4 index 0..767
    float4 w = *(const float4*)(wsrc + f * 4);
    int row = f >> 3, col = (f & 7) * 4;
    *(float4*)(&Ws[row * 36 + col]) = w;
  }
  // stage x: 1024 float4 (128 b x 32 c)
#pragma unroll
  for (int q = 0; q < 4; q++) {
    int p = t + 256 * q;                        // float4 index 0..1023
    int bl = p >> 3, c4 = p & 7;
    float4 v = *(const float4*)(x + ((size_t)bl * I_ + i) * CIN_ + c4 * 4);
    *(float4*)(&xs[bl * 36 + c4 * 4]) = v;
  }
  __syncthreads();

  const int oq = t & 3, bg = t >> 2;
  float4 acc[2][6];
#pragma unroll
  for (int bb = 0; bb < 2; bb++)
#pragma unroll
    for (int j = 0; j < 6; j++) acc[bb][j] = make_float4(0.f, 0.f, 0.f, 0.f);

#pragma unroll
  for (int cq = 0; cq < 8; cq++) {
    float4 xv[2];
    xv[0] = *(const float4*)(&xs[(bg * 2 + 0) * 36 + cq * 4]);
    xv[1] = *(const float4*)(&xs[(bg * 2 + 1) * 36 + cq * 4]);
#pragma unroll
    for (int j = 0; j < 6; j++) {
      const float* wb = &Ws[(j * 16 + oq * 4) * 36 + cq * 4];
      float4 w0 = *(const float4*)(wb);
      float4 w1 = *(const float4*)(wb + 36);
      float4 w2 = *(const float4*)(wb + 72);
      float4 w3 = *(const float4*)(wb + 108);
#pragma unroll
      for (int bb = 0; bb < 2; bb++) {
        acc[bb][j].x += w0.x * xv[bb].x + w0.y * xv[bb].y + w0.z * xv[bb].z + w0.w * xv[bb].w;
        acc[bb][j].y += w1.x * xv[bb].x + w1.y * xv[bb].y + w1.z * xv[bb].z + w1.w * xv[bb].w;
        acc[bb][j].z += w2.x * xv[bb].x + w2.y * xv[bb].y + w2.z * xv[bb].z + w2.w * xv[bb].w;
        acc[bb][j].w += w3.x * xv[bb].x + w3.y * xv[bb].y + w3.z * xv[bb].z + w3.w * xv[bb].w;
      }
    }
  }

#pragma unroll
  for (int bb = 0; bb < 2; bb++) {
    size_t base = ((size_t)(bg * 2 + bb) * I_ + i) * JO_;
#pragma unroll
    for (int j = 0; j < 6; j++)
      *(float4*)(&u_hat[base + j * 16 + oq * 4]) = acc[bb][j];
  }
}

// ---------------- r0: r0buf[ps][b][jo] = (1/6) * sum of 64 i of u_hat --------
__global__ __launch_bounds__(256) void r0_kernel(const float* __restrict__ u_hat,
                                                 float* __restrict__ r0buf) {
  int idx = blockIdx.x * 256 + threadIdx.x;      // 0..98303 (quad outputs)
  int joq = idx % 24;
  int rb = idx / 24;
  int b = rb % B_;
  int ps = rb / B_;                              // 0..31
  const float* src = u_hat + ((size_t)b * I_ + ps * 64) * JO_ + joq * 4;
  float4 s = make_float4(0.f, 0.f, 0.f, 0.f);
#pragma unroll 8
  for (int k = 0; k < 64; k++) {
    float4 v = *(const float4*)(src + (size_t)k * JO_);
    s.x += v.x; s.y += v.y; s.z += v.z; s.w += v.w;
  }
  const float c = 1.0f / 6.0f;
  *(float4*)(&r0buf[((size_t)ps * B_ + b) * JO_ + joq * 4]) =
      make_float4(s.x * c, s.y * c, s.z * c, s.w * c);
}

// ---------------- softmax over 6 (thread-local) ------------------------------
__device__ __forceinline__ void softmax6(const float* bv, float* s) {
  float m = fmaxf(fmaxf(fmaxf(bv[0], bv[1]), fmaxf(bv[2], bv[3])), fmaxf(bv[4], bv[5]));
  float e[6], sum = 0.0f;
#pragma unroll
  for (int j = 0; j < 6; j++) { e[j] = expf(bv[j] - m); sum += e[j]; }
  float inv = 1.0f / sum;
#pragma unroll
  for (int j = 0; j < 6; j++) s[j] = e[j] * inv;
}

// ---------------- g: one fused routing iteration -----------------------------
// grid (NCH=8, B=128), 256 thr. Computes v_t from prev partials (redundant per
// block), then dd / b-update / kde partial / next-iteration partials.
__global__ __launch_bounds__(256) void g_kernel(int t, int npart,
    const float* __restrict__ u_hat, float* __restrict__ b_buf,
    const float* __restrict__ gp_in, float* __restrict__ gp_out,
    const float* __restrict__ sp_in, float* __restrict__ sp_out,
    float* __restrict__ v_buf, float* __restrict__ kde_acc) {
  // reconstruct done/loss chain from kde slots (all threads, uniform)
  float last = 0.0f; bool done = false;
  for (int tau = 1; tau < t; ++tau) {
    float kde = logf(kde_acc[tau - 1] * (1.0f / 128.0f));
    bool conv = fabsf(kde - last) < 0.05f;
    if (!done) last = kde;
    done = done || conv;
  }
  if (done) return;                               // frozen: outputs already final

  const int t0 = threadIdx.x;
  const int b = blockIdx.y;
  const int chunk = blockIdx.x;

  __shared__ float vS[96], v2S[6], SS[6], iSS[6], gSc[6], slots[8][56];

  if (t0 < 6) { float s;
    if (t == 1) s = 2048.0f / 6.0f;
    else { s = 0.0f; for (int c = 0; c < NCH; c++) s += sp_in[(c * B_ + b) * J_ + t0]; }
    SS[t0] = s; iSS[t0] = 1.0f / s; }
  __syncthreads();
  if (t0 < 96) { float u = 0;
    for (int c = 0; c < npart; c++) u += gp_in[((size_t)c * B_ + b) * JO_ + t0];
    vS[t0] = u / SS[t0 >> 4]; }                   // pre-squash v
  __syncthreads();
  if (t0 < 6) { float s2 = 0;
    for (int o = 0; o < 16; o++) { float v = vS[t0 * 16 + o]; s2 += v * v; }
    float g = sqrtf(s2) / (0.5f + s2); gSc[t0] = g; v2S[t0] = g * g * s2; }
  __syncthreads();
  if (t0 < 96) { float v = vS[t0] * gSc[t0 >> 4]; vS[t0] = v;
    if (chunk == 0) v_buf[b * JO_ + t0] = v; }    // commit v_t (only if active)
  __syncthreads();

  const int h = t0 & 1;                           // o-half
  float Upart[6][8] = {}; float sPart[6] = {}; float cdd = 0.0f;

#pragma unroll 1
  for (int half = 0; half < 2; ++half) {
    int i = chunk * 256 + half * 128 + (t0 >> 1);
    size_t bbase = ((size_t)b * I_ + i) * J_;
    float bo[6], sm[6];
#pragma unroll
    for (int j = 0; j < 6; j++) bo[j] = b_buf[bbase + j];
    softmax6(bo, sm);                             // s_t (c_t = s_t / S_t)

    const float* urow = u_hat + ((size_t)b * I_ + i) * JO_ + h * 8;
    float dd[6];
#pragma unroll
    for (int j = 0; j < 6; j++) {
      float4 ua = *(const float4*)(urow + j * 16);
      float4 ub = *(const float4*)(urow + j * 16 + 4);
      float4 va = *(const float4*)(&vS[j * 16 + h * 8]);
      float4 vb = *(const float4*)(&vS[j * 16 + h * 8 + 4]);
      float p2 = ua.x*ua.x + ua.y*ua.y + ua.z*ua.z + ua.w*ua.w
               + ub.x*ub.x + ub.y*ub.y + ub.z*ub.z + ub.w*ub.w;
      float pd = ua.x*va.x + ua.y*va.y + ua.z*va.z + ua.w*va.w
               + ub.x*vb.x + ub.y*vb.y + ub.z*vb.z + ub.w*vb.w;
      p2 += __shfl_xor(p2, 1);                    // full |u|^2 over 16 o
      pd += __shfl_xor(pd, 1);                    // full u.v
      float g = sqrtf(p2) / (0.5f + p2);          // squash scale of u_hat
      dd[j] = 1.0f - (g * g * p2 - 2.0f * g * pd + v2S[j]);
    }
    float bn[6], sn[6];
#pragma unroll
    for (int j = 0; j < 6; j++) bn[j] = bo[j] + dd[j];
    if (h == 0) {
#pragma unroll
      for (int j = 0; j < 6; j++) b_buf[bbase + j] = bn[j];
      float cs = 0.0f;
#pragma unroll
      for (int j = 0; j < 6; j++) cs += (sm[j] * iSS[j]) * dd[j];
      cdd += cs;
    }
    softmax6(bn, sn);                             // s_{t+1}
    if (h == 0) {
#pragma unroll
      for (int j = 0; j < 6; j++) sPart[j] += sn[j];
    }
#pragma unroll
    for (int j = 0; j < 6; j++) {                 // reload u (L1/L2-hot) to cut regs
      float4 ua = *(const float4*)(urow + j * 16);
      float4 ub = *(const float4*)(urow + j * 16 + 4);
      Upart[j][0] += sn[j] * ua.x; Upart[j][1] += sn[j] * ua.y;
      Upart[j][2] += sn[j] * ua.z; Upart[j][3] += sn[j] * ua.w;
      Upart[j][4] += sn[j] * ub.x; Upart[j][5] += sn[j] * ub.y;
      Upart[j][6] += sn[j] * ub.z; Upart[j][7] += sn[j] * ub.w;
    }
  }

  // same-parity butterfly (bits 1..5): sums the 32 lanes sharing this h
#pragma unroll
  for (int m = 2; m <= 32; m <<= 1) {
#pragma unroll
    for (int j = 0; j < 6; j++) {
#pragma unroll
      for (int r = 0; r < 8; r++) Upart[j][r] += __shfl_xor(Upart[j][r], m);
      sPart[j] += __shfl_xor(sPart[j], m);
    }
    cdd += __shfl_xor(cdd, m);
  }
  int lane = t0 & 63, w = t0 >> 6;
  if (lane < 2) {
#pragma unroll
    for (int j = 0; j < 6; j++) {
#pragma unroll
      for (int r = 0; r < 8; r++) slots[w * 2 + lane][j * 8 + r] = Upart[j][r];
      slots[w * 2 + lane][48 + j] = sPart[j];
    }
    slots[w * 2 + lane][54] = cdd;
  }
  __syncthreads();
  if (t0 < 96) {
    int j = t0 >> 4, o = t0 & 15, hh = o >> 3, r = o & 7;
    float s = slots[0 + hh][j * 8 + r] + slots[2 + hh][j * 8 + r] +
              slots[4 + hh][j * 8 + r] + slots[6 + hh][j * 8 + r];
    gp_out[((size_t)chunk * B_ + b) * JO_ + t0] = s;
  } else if (t0 < 102) {
    int j = t0 - 96;
    float s = slots[0][48 + j] + slots[2][48 + j] + slots[4][48 + j] + slots[6][48 + j];
    sp_out[(chunk * B_ + b) * J_ + j] = s;
  } else if (t0 == 102) {
    float s = slots[0][54] + slots[2][54] + slots[4][54] + slots[6][54];
    atomicAdd(&kde_acc[t - 1], s);
  }
}

// ---------------- final: poses = v, activations = |v| ------------------------
__global__ __launch_bounds__(256) void final_kernel(const float* __restrict__ v_buf,
                                                    float* __restrict__ out) {
  int idx = blockIdx.x * 256 + threadIdx.x;       // 0..12287 = b*96 + j*16 + o
  float v = v_buf[idx];
  out[idx] = v;
  float p = v * v;
  p += __shfl_xor(p, 1); p += __shfl_xor(p, 2);
  p += __shfl_xor(p, 4); p += __shfl_xor(p, 8);
  if ((idx & 15) == 0) out[B_ * JO_ + (idx >> 4)] = sqrtf(p);
}

// ---------------- launch -----------------------------------------------------
extern "C" void kernel_launch(void* const* d_in, const int* in_sizes, int n_in,
                              void* d_out, int out_size, void* d_ws, size_t ws_size,
                              hipStream_t stream) {
  const float* x  = (const float*)d_in[0];
  const float* W1 = (const float*)d_in[2];        // d_in[1] = y, unused by reference

  float* ws    = (float*)d_ws;
  float* u_hat = ws;                                        // 25,165,824
  float* b_buf = u_hat + (size_t)B_ * I_ * JO_;             //  1,572,864
  float* r0buf = b_buf + (size_t)B_ * I_ * J_;              //    393,216
  float* gp    = r0buf + (size_t)NPS * B_ * JO_;            //  2 * 98,304
  float* sp    = gp + 2 * (size_t)NCH * B_ * JO_;           //  2 * 6,144
  float* v_buf = sp + 2 * (size_t)NCH * B_ * J_;            //     12,288
  float* kde   = v_buf + (size_t)B_ * JO_;                  //     16

  init_kernel<<<(B_ * I_ * J_) / 256, 256, 0, stream>>>(b_buf, kde);
  p0_kernel<<<I_, 256, 0, stream>>>(x, W1, u_hat);
  r0_kernel<<<(NPS * B_ * JO_ / 4) / 256, 256, 0, stream>>>(u_hat, r0buf);
  for (int t = 1; t <= MAXIT; t++)
    g_kernel<<<dim3(NCH, B_), 256, 0, stream>>>(t, (t == 1) ? NPS : NCH, u_hat, b_buf,
        (t == 1) ? r0buf : gp + ((t - 1) & 1) * (NCH * B_ * JO_),
        gp + (t & 1) * (NCH * B_ * JO_),
        sp + ((t - 1) & 1) * (NCH * B_ * J_),  sp + (t & 1) * (NCH * B_ * J_),
        v_buf, kde);
  final_kernel<<<(B_ * JO_) / 256, 256, 0, stream>>>(v_buf, (float*)d_out);
}

// Round 9
// 289.402 us; speedup vs baseline: 4.3233x; 2.3499x over previous
//
#include <hip/hip_runtime.h>
#include <math.h>

// FCCaps dynamic routing, MI355X.
// Shapes: B=128, I=2048, J=6 (OUT_CAPS of 8), O=16, Cin=32, MAX_ITERS=16.
// Pipeline: init -> p0 (u_hat einsum, 1 i/block, float4 stores)
//           -> r0 (Sum_i u_hat partials from L3, 32 psets)
//           -> 16x g (fused routing iteration, device-side early-exit)
//           -> final (poses + activations).

#define B_    128
#define I_    2048
#define J_    6
#define O_    16
#define JO_   96
#define CIN_  32
#define MAXIT 16
#define NCH   8            // i-chunks for g kernel (256 i each)
#define NPS   32           // i-subchunks for r0 (64 i each)

// ---------------- init: zero b logits, zero kde slots ------------------------
__global__ __launch_bounds__(256) void init_kernel(float* __restrict__ b_buf,
                                                   float* __restrict__ kde_acc) {
  int idx = blockIdx.x * 256 + threadIdx.x;
  b_buf[idx] = 0.0f;                               // grid sized exactly B*I*J
  if (idx < MAXIT) kde_acc[idx] = 0.0f;
}

// ---------------- p0: u_hat[b][i][jo] = sum_c W1[i][jo][c] * x[b][i][c] ------
// One i per block. 256 thr: oq = t&3 (owns o = oq*4..+3), bg = t>>2 (2 b each).
// LDS: W[96][36] + x[128][36] (pad 36 kills power-of-2 bank strides).
// NOTE 1: __launch_bounds__(256,4) caps VGPR at 64 -> acc spills -> 3.4 GB
//         HBM traffic, 1 ms (round-4). Keep plain (256).
// NOTE 2: full unroll of the cq loop batches 8 iterations of LDS w-loads ->
//         live set > 256 VGPR -> still spills (round-6: VGPR=256, 1.5 GB
//         traffic, 443 us). Keep #pragma unroll 1.
__global__ __launch_bounds__(256) void p0_kernel(const float* __restrict__ x,
                                                 const float* __restrict__ W1,
                                                 float* __restrict__ u_hat) {
  __shared__ float Ws[96 * 36];
  __shared__ float xs[128 * 36];
  const int t = threadIdx.x;
  const int i = blockIdx.x;

  // stage W: 768 float4 (only first 3072 floats of the 4096-float row, j<6)
  const float* wsrc = W1 + (size_t)i * 4096;
#pragma unroll
  for (int q = 0; q < 3; q++) {
    int f = t + 256 * q;                        // float4 index 0..767
    float4 w = *(const float4*)(wsrc + f * 4);
    int row = f >> 3, col = (f & 7) * 4;
    *(float4*)(&Ws[row * 36 + col]) = w;
  }
  // stage x: 1024 float4 (128 b x 32 c)
#pragma unroll
  for (int q = 0; q < 4; q++) {
    int p = t + 256 * q;                        // float4 index 0..1023
    int bl = p >> 3, c4 = p & 7;
    float4 v = *(const float4*)(x + ((size_t)bl * I_ + i) * CIN_ + c4 * 4);
    *(float4*)(&xs[bl * 36 + c4 * 4]) = v;
  }
  __syncthreads();

  const int oq = t & 3, bg = t >> 2;
  float4 acc[2][6];
#pragma unroll
  for (int bb = 0; bb < 2; bb++)
#pragma unroll
    for (int j = 0; j < 6; j++) acc[bb][j] = make_float4(0.f, 0.f, 0.f, 0.f);

#pragma unroll 1
  for (int cq = 0; cq < 8; cq++) {
    float4 xv[2];
    xv[0] = *(const float4*)(&xs[(bg * 2 + 0) * 36 + cq * 4]);
    xv[1] = *(const float4*)(&xs[(bg * 2 + 1) * 36 + cq * 4]);
#pragma unroll
    for (int j = 0; j < 6; j++) {
      const float* wb = &Ws[(j * 16 + oq * 4) * 36 + cq * 4];
      float4 w0 = *(const float4*)(wb);
      float4 w1 = *(const float4*)(wb + 36);
      float4 w2 = *(const float4*)(wb + 72);
      float4 w3 = *(const float4*)(wb + 108);
#pragma unroll
      for (int bb = 0; bb < 2; bb++) {
        acc[bb][j].x += w0.x * xv[bb].x + w0.y * xv[bb].y + w0.z * xv[bb].z + w0.w * xv[bb].w;
        acc[bb][j].y += w1.x * xv[bb].x + w1.y * xv[bb].y + w1.z * xv[bb].z + w1.w * xv[bb].w;
        acc[bb][j].z += w2.x * xv[bb].x + w2.y * xv[bb].y + w2.z * xv[bb].z + w2.w * xv[bb].w;
        acc[bb][j].w += w3.x * xv[bb].x + w3.y * xv[bb].y + w3.z * xv[bb].z + w3.w * xv[bb].w;
      }
    }
  }

#pragma unroll
  for (int bb = 0; bb < 2; bb++) {
    size_t base = ((size_t)(bg * 2 + bb) * I_ + i) * JO_;
#pragma unroll
    for (int j = 0; j < 6; j++)
      *(float4*)(&u_hat[base + j * 16 + oq * 4]) = acc[bb][j];
  }
}

// ---------------- r0: r0buf[ps][b][jo] = (1/6) * sum of 64 i of u_hat --------
__global__ __launch_bounds__(256) void r0_kernel(const float* __restrict__ u_hat,
                                                 float* __restrict__ r0buf) {
  int idx = blockIdx.x * 256 + threadIdx.x;      // 0..98303 (quad outputs)
  int joq = idx % 24;
  int rb = idx / 24;
  int b = rb % B_;
  int ps = rb / B_;                              // 0..31
  const float* src = u_hat + ((size_t)b * I_ + ps * 64) * JO_ + joq * 4;
  float4 s = make_float4(0.f, 0.f, 0.f, 0.f);
#pragma unroll 8
  for (int k = 0; k < 64; k++) {
    float4 v = *(const float4*)(src + (size_t)k * JO_);
    s.x += v.x; s.y += v.y; s.z += v.z; s.w += v.w;
  }
  const float c = 1.0f / 6.0f;
  *(float4*)(&r0buf[((size_t)ps * B_ + b) * JO_ + joq * 4]) =
      make_float4(s.x * c, s.y * c, s.z * c, s.w * c);
}

// ---------------- softmax over 6 (thread-local) ------------------------------
__device__ __forceinline__ void softmax6(const float* bv, float* s) {
  float m = fmaxf(fmaxf(fmaxf(bv[0], bv[1]), fmaxf(bv[2], bv[3])), fmaxf(bv[4], bv[5]));
  float e[6], sum = 0.0f;
#pragma unroll
  for (int j = 0; j < 6; j++) { e[j] = expf(bv[j] - m); sum += e[j]; }
  float inv = 1.0f / sum;
#pragma unroll
  for (int j = 0; j < 6; j++) s[j] = e[j] * inv;
}

// ---------------- g: one fused routing iteration -----------------------------
// grid (NCH=8, B=128), 256 thr. Computes v_t from prev partials (redundant per
// block), then dd / b-update / kde partial / next-iteration partials.
__global__ __launch_bounds__(256) void g_kernel(int t, int npart,
    const float* __restrict__ u_hat, float* __restrict__ b_buf,
    const float* __restrict__ gp_in, float* __restrict__ gp_out,
    const float* __restrict__ sp_in, float* __restrict__ sp_out,
    float* __restrict__ v_buf, float* __restrict__ kde_acc) {
  // reconstruct done/loss chain from kde slots (all threads, uniform)
  float last = 0.0f; bool done = false;
  for (int tau = 1; tau < t; ++tau) {
    float kde = logf(kde_acc[tau - 1] * (1.0f / 128.0f));
    bool conv = fabsf(kde - last) < 0.05f;
    if (!done) last = kde;
    done = done || conv;
  }
  if (done) return;                               // frozen: outputs already final

  const int t0 = threadIdx.x;
  const int b = blockIdx.y;
  const int chunk = blockIdx.x;

  __shared__ float vS[96], v2S[6], SS[6], iSS[6], gSc[6], slots[8][56];

  if (t0 < 6) { float s;
    if (t == 1) s = 2048.0f / 6.0f;
    else { s = 0.0f; for (int c = 0; c < NCH; c++) s += sp_in[(c * B_ + b) * J_ + t0]; }
    SS[t0] = s; iSS[t0] = 1.0f / s; }
  __syncthreads();
  if (t0 < 96) { float u = 0;
    for (int c = 0; c < npart; c++) u += gp_in[((size_t)c * B_ + b) * JO_ + t0];
    vS[t0] = u / SS[t0 >> 4]; }                   // pre-squash v
  __syncthreads();
  if (t0 < 6) { float s2 = 0;
    for (int o = 0; o < 16; o++) { float v = vS[t0 * 16 + o]; s2 += v * v; }
    float g = sqrtf(s2) / (0.5f + s2); gSc[t0] = g; v2S[t0] = g * g * s2; }
  __syncthreads();
  if (t0 < 96) { float v = vS[t0] * gSc[t0 >> 4]; vS[t0] = v;
    if (chunk == 0) v_buf[b * JO_ + t0] = v; }    // commit v_t (only if active)
  __syncthreads();

  const int h = t0 & 1;                           // o-half
  float Upart[6][8] = {}; float sPart[6] = {}; float cdd = 0.0f;

#pragma unroll 1
  for (int half = 0; half < 2; ++half) {
    int i = chunk * 256 + half * 128 + (t0 >> 1);
    size_t bbase = ((size_t)b * I_ + i) * J_;
    float bo[6], sm[6];
#pragma unroll
    for (int j = 0; j < 6; j++) bo[j] = b_buf[bbase + j];
    softmax6(bo, sm);                             // s_t (c_t = s_t / S_t)

    const float* urow = u_hat + ((size_t)b * I_ + i) * JO_ + h * 8;
    float dd[6];
#pragma unroll
    for (int j = 0; j < 6; j++) {
      float4 ua = *(const float4*)(urow + j * 16);
      float4 ub = *(const float4*)(urow + j * 16 + 4);
      float4 va = *(const float4*)(&vS[j * 16 + h * 8]);
      float4 vb = *(const float4*)(&vS[j * 16 + h * 8 + 4]);
      float p2 = ua.x*ua.x + ua.y*ua.y + ua.z*ua.z + ua.w*ua.w
               + ub.x*ub.x + ub.y*ub.y + ub.z*ub.z + ub.w*ub.w;
      float pd = ua.x*va.x + ua.y*va.y + ua.z*va.z + ua.w*va.w
               + ub.x*vb.x + ub.y*vb.y + ub.z*vb.z + ub.w*vb.w;
      p2 += __shfl_xor(p2, 1);                    // full |u|^2 over 16 o
      pd += __shfl_xor(pd, 1);                    // full u.v
      float g = sqrtf(p2) / (0.5f + p2);          // squash scale of u_hat
      dd[j] = 1.0f - (g * g * p2 - 2.0f * g * pd + v2S[j]);
    }
    float bn[6], sn[6];
#pragma unroll
    for (int j = 0; j < 6; j++) bn[j] = bo[j] + dd[j];
    if (h == 0) {
#pragma unroll
      for (int j = 0; j < 6; j++) b_buf[bbase + j] = bn[j];
      float cs = 0.0f;
#pragma unroll
      for (int j = 0; j < 6; j++) cs += (sm[j] * iSS[j]) * dd[j];
      cdd += cs;
    }
    softmax6(bn, sn);                             // s_{t+1}
    if (h == 0) {
#pragma unroll
      for (int j = 0; j < 6; j++) sPart[j] += sn[j];
    }
#pragma unroll
    for (int j = 0; j < 6; j++) {                 // reload u (L1/L2-hot) to cut regs
      float4 ua = *(const float4*)(urow + j * 16);
      float4 ub = *(const float4*)(urow + j * 16 + 4);
      Upart[j][0] += sn[j] * ua.x; Upart[j][1] += sn[j] * ua.y;
      Upart[j][2] += sn[j] * ua.z; Upart[j][3] += sn[j] * ua.w;
      Upart[j][4] += sn[j] * ub.x; Upart[j][5] += sn[j] * ub.y;
      Upart[j][6] += sn[j] * ub.z; Upart[j][7] += sn[j] * ub.w;
    }
  }

  // same-parity butterfly (bits 1..5): sums the 32 lanes sharing this h
#pragma unroll
  for (int m = 2; m <= 32; m <<= 1) {
#pragma unroll
    for (int j = 0; j < 6; j++) {
#pragma unroll
      for (int r = 0; r < 8; r++) Upart[j][r] += __shfl_xor(Upart[j][r], m);
      sPart[j] += __shfl_xor(sPart[j], m);
    }
    cdd += __shfl_xor(cdd, m);
  }
  int lane = t0 & 63, w = t0 >> 6;
  if (lane < 2) {
#pragma unroll
    for (int j = 0; j < 6; j++) {
#pragma unroll
      for (int r = 0; r < 8; r++) slots[w * 2 + lane][j * 8 + r] = Upart[j][r];
      slots[w * 2 + lane][48 + j] = sPart[j];
    }
    slots[w * 2 + lane][54] = cdd;
  }
  __syncthreads();
  if (t0 < 96) {
    int j = t0 >> 4, o = t0 & 15, hh = o >> 3, r = o & 7;
    float s = slots[0 + hh][j * 8 + r] + slots[2 + hh][j * 8 + r] +
              slots[4 + hh][j * 8 + r] + slots[6 + hh][j * 8 + r];
    gp_out[((size_t)chunk * B_ + b) * JO_ + t0] = s;
  } else if (t0 < 102) {
    int j = t0 - 96;
    float s = slots[0][48 + j] + slots[2][48 + j] + slots[4][48 + j] + slots[6][48 + j];
    sp_out[(chunk * B_ + b) * J_ + j] = s;
  } else if (t0 == 102) {
    float s = slots[0][54] + slots[2][54] + slots[4][54] + slots[6][54];
    atomicAdd(&kde_acc[t - 1], s);
  }
}

// ---------------- final: poses = v, activations = |v| ------------------------
__global__ __launch_bounds__(256) void final_kernel(const float* __restrict__ v_buf,
                                                    float* __restrict__ out) {
  int idx = blockIdx.x * 256 + threadIdx.x;       // 0..12287 = b*96 + j*16 + o
  float v = v_buf[idx];
  out[idx] = v;
  float p = v * v;
  p += __shfl_xor(p, 1); p += __shfl_xor(p, 2);
  p += __shfl_xor(p, 4); p += __shfl_xor(p, 8);
  if ((idx & 15) == 0) out[B_ * JO_ + (idx >> 4)] = sqrtf(p);
}

// ---------------- launch -----------------------------------------------------
extern "C" void kernel_launch(void* const* d_in, const int* in_sizes, int n_in,
                              void* d_out, int out_size, void* d_ws, size_t ws_size,
                              hipStream_t stream) {
  const float* x  = (const float*)d_in[0];
  const float* W1 = (const float*)d_in[2];        // d_in[1] = y, unused by reference

  float* ws    = (float*)d_ws;
  float* u_hat = ws;                                        // 25,165,824
  float* b_buf = u_hat + (size_t)B_ * I_ * JO_;             //  1,572,864
  float* r0buf = b_buf + (size_t)B_ * I_ * J_;              //    393,216
  float* gp    = r0buf + (size_t)NPS * B_ * JO_;            //  2 * 98,304
  float* sp    = gp + 2 * (size_t)NCH * B_ * JO_;           //  2 * 6,144
  float* v_buf = sp + 2 * (size_t)NCH * B_ * J_;            //     12,288
  float* kde   = v_buf + (size_t)B_ * JO_;                  //     16

  init_kernel<<<(B_ * I_ * J_) / 256, 256, 0, stream>>>(b_buf, kde);
  p0_kernel<<<I_, 256, 0, stream>>>(x, W1, u_hat);
  r0_kernel<<<(NPS * B_ * JO_ / 4) / 256, 256, 0, stream>>>(u_hat, r0buf);
  for (int t = 1; t <= MAXIT; t++)
    g_kernel<<<dim3(NCH, B_), 256, 0, stream>>>(t, (t == 1) ? NPS : NCH, u_hat, b_buf,
        (t == 1) ? r0buf : gp + ((t - 1) & 1) * (NCH * B_ * JO_),
        gp + (t & 1) * (NCH * B_ * JO_),
        sp + ((t - 1) & 1) * (NCH * B_ * J_),  sp + (t & 1) * (NCH * B_ * J_),
        v_buf, kde);
  final_kernel<<<(B_ * JO_) / 256, 256, 0, stream>>>(v_buf, (float*)d_out);
}